// Round 4
// baseline (182.864 us; speedup 1.0000x reference)
//
#include <hip/hip_runtime.h>
#include <hip/hip_bf16.h>
#include <math.h>

// KAN layer: out = GELU( einsum('bik,ikj->bj', x^k, W) + bias ),
//   B=4096, D=1024, K=5, U=1024.
//
// Round 4: (1) k=0 plane folded into bias (GEMM K=4096). (2) NO LDS GEMM:
// B operand pre-packed in MFMA fragment order (1 KB units; lane l holds
// row l&15, k-octet l>>4), loaded global->VGPR as dwordx4 directly. A operand
// is never materialized: each lane loads its two x values (float2) and builds
// the bf16 power-fragment in registers (6 mul + pack). No barriers; 1-deep
// register prefetch; blockIdx.x = n-tile so each XCD's L2 holds one 1 MB
// B-slice (round-robin XCD heuristic).

#define B_DIM 4096
#define D_DIM 1024
#define U_DIM 1024
#define KT2 4096            // GEMM K after dropping k=0 plane
#define NKB 128             // 32-wide k-blocks

typedef unsigned short ushort_t;
typedef __attribute__((ext_vector_type(8))) short bf16x8;   // MFMA A/B frag
typedef __attribute__((ext_vector_type(4))) float f32x4;    // MFMA C/D frag

__device__ __forceinline__ ushort_t f2bf(float f) {   // RNE (prep kernels)
  union { float f; unsigned int u; } v;
  v.f = f;
  unsigned int r = v.u + 0x7FFFu + ((v.u >> 16) & 1u);
  return (ushort_t)(r >> 16);
}

__device__ __forceinline__ float gelu_exact(float v) {
  return 0.5f * v * (1.0f + erff(v * 0.70710678118654752f));
}

// A-fragment from two x values: 8 bf16 = {xa,xa^2,xa^3,xa^4, xb,xb^2,xb^3,xb^4}
// round-half-away pack (|err| <= ulp/2, same bound as RNE).
__device__ __forceinline__ bf16x8 build_afrag(float xa, float xb) {
  const float a2 = xa * xa, b2 = xb * xb;
  float p[8] = {xa, a2, a2 * xa, a2 * a2, xb, b2, b2 * xb, b2 * b2};
  union { bf16x8 v; unsigned int d[4]; } r;
#pragma unroll
  for (int i = 0; i < 4; ++i) {
    union { float f; unsigned int u; } lo, hi;
    lo.f = p[2 * i];
    hi.f = p[2 * i + 1];
    const unsigned int ul = lo.u + 0x8000u;
    const unsigned int uh = hi.u + 0x8000u;
    r.d[i] = (ul >> 16) | (uh & 0xFFFF0000u);
  }
  return r.v;
}

// packed addr (ushorts) of (row, k): ((row>>4)*NKB + (k>>5))*512
//                                     + (((k>>3)&3)*16 + (row&15))*8 + (k&7)

// ---------------- prep 1: W -> B_packed (planes 1..4) ----------------
__global__ __launch_bounds__(256) void w_pack_kernel(
    const float* __restrict__ W, ushort_t* __restrict__ Bp) {
  const int t    = threadIdx.x;
  const int wave = t >> 6;
  const int lane = t & 63;
  const int kblk = blockIdx.x * 4 + wave;     // 0..127
  const int n16  = blockIdx.y;                // 0..63
  const int jj   = lane & 15;
  const int ko   = lane >> 4;
  const int j    = n16 * 16 + jj;
  const int i0   = kblk * 8 + ko * 2;

  ushort_t o[8];
#pragma unroll
  for (int t2 = 0; t2 < 2; ++t2) {
    const int i = i0 + t2;
#pragma unroll
    for (int e = 0; e < 4; ++e) {
      const int r = i * 5 + e + 1;            // skip k=0 plane
      o[t2 * 4 + e] = f2bf(W[(size_t)r * U_DIM + j]);
    }
  }
  *(uint4*)(Bp + ((size_t)n16 * NKB + kblk) * 512 + lane * 8) = *(const uint4*)o;
}

// ---------------- prep 2: fold k=0 plane into bias ----------------
__global__ __launch_bounds__(256) void fold_part_kernel(
    const float* __restrict__ W, float* __restrict__ part) {
  const int j = blockIdx.x * 256 + threadIdx.x;   // grid.x = 4
  const int g = blockIdx.y;                        // 0..31
  float s = 0.0f;
#pragma unroll 8
  for (int ii = 0; ii < 32; ++ii) {
    const int i = g * 32 + ii;
    s += W[(size_t)(i * 5) * U_DIM + j];
  }
  part[(size_t)g * U_DIM + j] = s;
}

__global__ __launch_bounds__(256) void fold_final_kernel(
    const float* __restrict__ part, const float* __restrict__ bias,
    float* __restrict__ bias2) {
  const int j = blockIdx.x * 256 + threadIdx.x;   // grid.x = 4
  float s = bias[j];
#pragma unroll
  for (int g = 0; g < 32; ++g) s += part[(size_t)g * U_DIM + j];
  bias2[j] = s;
}

// ---------------- main GEMM: 64x128 tile, no LDS, register pipeline ----------------
__global__ __launch_bounds__(256, 2) void gemm_kernel(
    const float* __restrict__ x, const ushort_t* __restrict__ Bp,
    const float* __restrict__ bias2, float* __restrict__ C) {
  const int tid  = threadIdx.x;
  const int wave = tid >> 6;
  const int lane = tid & 63;
  const int wm   = wave >> 1;             // 0..1 : 32-row half
  const int wn   = wave & 1;              // 0..1 : 64-col half
  const int n16b = blockIdx.x * 8;        // N=128 -> 8 n16 blocks
  const int m16b = blockIdx.y * 4;        // M=64  -> 4 m16 blocks

  // x source for the two A-frags: lane l covers row (m16*16 + (l&15)),
  // i-pair i0 = kb*8 + (l>>4)*2  ->  k = i*4 + (power-1)
  const float* xptr[2];
#pragma unroll
  for (int mf = 0; mf < 2; ++mf)
    xptr[mf] = x + (size_t)((m16b + wm * 2 + mf) * 16 + (lane & 15)) * D_DIM
                 + (lane >> 4) * 2;

  // B units, fragment-order: dwordx4 at unit base + lane*16B
  const ushort_t* bptr[4];
#pragma unroll
  for (int nf = 0; nf < 4; ++nf)
    bptr[nf] = Bp + ((size_t)(n16b + wn * 4 + nf) * NKB) * 512 + lane * 8;

  f32x4 acc[2][4];
  const f32x4 zero = {0.0f, 0.0f, 0.0f, 0.0f};
#pragma unroll
  for (int mf = 0; mf < 2; ++mf)
#pragma unroll
    for (int nf = 0; nf < 4; ++nf) acc[mf][nf] = zero;

  // 1-deep register prefetch pipeline, no barriers anywhere
  float2 xc[2];
  bf16x8 bc[4];
#pragma unroll
  for (int mf = 0; mf < 2; ++mf) xc[mf] = *(const float2*)xptr[mf];
#pragma unroll
  for (int nf = 0; nf < 4; ++nf) bc[nf] = *(const bf16x8*)bptr[nf];

#pragma unroll 2
  for (int kb = 0; kb < NKB; ++kb) {
    float2 xn[2];
    bf16x8 bn[4];
    if (kb + 1 < NKB) {
#pragma unroll
      for (int mf = 0; mf < 2; ++mf)
        xn[mf] = *(const float2*)(xptr[mf] + (size_t)(kb + 1) * 8);
#pragma unroll
      for (int nf = 0; nf < 4; ++nf)
        bn[nf] = *(const bf16x8*)(bptr[nf] + (size_t)(kb + 1) * 512);
    }

    const bf16x8 a0 = build_afrag(xc[0].x, xc[0].y);
    const bf16x8 a1 = build_afrag(xc[1].x, xc[1].y);
#pragma unroll
    for (int nf = 0; nf < 4; ++nf) {
      acc[0][nf] = __builtin_amdgcn_mfma_f32_16x16x32_bf16(a0, bc[nf], acc[0][nf], 0, 0, 0);
      acc[1][nf] = __builtin_amdgcn_mfma_f32_16x16x32_bf16(a1, bc[nf], acc[1][nf], 0, 0, 0);
    }

#pragma unroll
    for (int mf = 0; mf < 2; ++mf) xc[mf] = xn[mf];
#pragma unroll
    for (int nf = 0; nf < 4; ++nf) bc[nf] = bn[nf];
  }

  // epilogue: C/D map: col = lane&15, row = (lane>>4)*4 + reg
  const int crow0 = m16b * 16 + wm * 32 + (lane >> 4) * 4;
  const int ccol0 = n16b * 16 + wn * 64 + (lane & 15);
#pragma unroll
  for (int nf = 0; nf < 4; ++nf) {
    const int col = ccol0 + nf * 16;
    const float bv = bias2[col];
#pragma unroll
    for (int mf = 0; mf < 2; ++mf) {
#pragma unroll
      for (int r = 0; r < 4; ++r) {
        const int row = crow0 + mf * 16 + r;
        C[(size_t)row * U_DIM + col] = gelu_exact(acc[mf][nf][r] + bv);
      }
    }
  }
}

// ---------------- fallback (ws too small): fp32, no workspace ----------------
__global__ void fallback_kernel(const float* __restrict__ x, const float* __restrict__ W,
                                const float* __restrict__ bias, float* __restrict__ out) {
  int j  = blockIdx.x * 256 + threadIdx.x;
  int b0 = blockIdx.y * 16;
  float acc[16];
#pragma unroll
  for (int t = 0; t < 16; ++t) acc[t] = 0.0f;
  for (int i = 0; i < D_DIM; ++i) {
    const float* wr = W + (size_t)i * 5 * U_DIM + j;
    float w0 = wr[0 * U_DIM], w1 = wr[1 * U_DIM], w2 = wr[2 * U_DIM];
    float w3 = wr[3 * U_DIM], w4 = wr[4 * U_DIM];
#pragma unroll
    for (int t = 0; t < 16; ++t) {
      float xv = x[(size_t)(b0 + t) * D_DIM + i];
      float x2 = xv * xv;
      acc[t] += w0 + xv * w1 + x2 * w2 + x2 * xv * w3 + x2 * x2 * w4;
    }
  }
  float bv = bias[j];
#pragma unroll
  for (int t = 0; t < 16; ++t)
    out[(size_t)(b0 + t) * U_DIM + j] = gelu_exact(acc[t] + bv);
}

extern "C" void kernel_launch(void* const* d_in, const int* in_sizes, int n_in,
                              void* d_out, int out_size, void* d_ws, size_t ws_size,
                              hipStream_t stream) {
  const float* x    = (const float*)d_in[0];   // (4096, 1024)
  const float* W    = (const float*)d_in[1];   // (1024, 5, 1024), row r = i*5+k
  const float* bias = (const float*)d_in[2];   // (1024,)
  float* out = (float*)d_out;                  // (4096, 1024) fp32

  const size_t szB = (size_t)U_DIM * KT2 * sizeof(ushort_t);   //  8.39 MB
  const size_t szP = (size_t)32 * U_DIM * sizeof(float);       //  128 KB
  const size_t szb = (size_t)U_DIM * sizeof(float);            //    4 KB

  if (ws_size >= szB + szP + szb) {
    ushort_t* Bp   = (ushort_t*)d_ws;
    float*    part = (float*)((char*)d_ws + szB);
    float*    b2   = (float*)((char*)d_ws + szB + szP);
    w_pack_kernel<<<dim3(NKB / 4, U_DIM / 16), 256, 0, stream>>>(W, Bp);
    fold_part_kernel<<<dim3(U_DIM / 256, 32), 256, 0, stream>>>(W, part);
    fold_final_kernel<<<dim3(U_DIM / 256), 256, 0, stream>>>(part, bias, b2);
    gemm_kernel<<<dim3(U_DIM / 128, B_DIM / 64), 256, 0, stream>>>(x, Bp, b2, out);
  } else {
    fallback_kernel<<<dim3(U_DIM / 256, B_DIM / 16), 256, 0, stream>>>(x, W, bias, out);
  }
}